// Round 3
// baseline (196.148 us; speedup 1.0000x reference)
//
#include <hip/hip_runtime.h>

#define BB 8
#define CC 768
#define NN 256
#define HH 12
#define DD 64
#define K3 3072          // H*N = flattened (h,n) axis
#define BCN 196608       // C*N per batch
#define SCALE 0.125f     // D^-0.5 = 64^-0.5

// ---------------------------------------------------------------------------
// Algebra (all einops reshapes are flat-view reinterprets; no data movement):
//   x_view[b,d,k]   = x_ori flat [768*256] viewed [64,3072]   (k = h*256+n)
//   cp_view[b,d,k]  = cp    flat viewed [64,3072]
//   cr_view[b,d,k]  = cross flat viewed [64,3072]
//   atten = x_view^T cp_view * scale  (no softmax!)  -> associativity:
//   out   = atten @ cr_view^T  =  x_view^T @ (scale * cp_view @ cr_view^T)
//                               = x_view^T @ M,   M: [64,64] per batch
//   U = x_view^T M : flat [3072,64] == [256,768]  ((N H) regroup is a no-op)
//   y = U2 @ Wd^T + bd ; out[b,o,n] = x_ori[b,o,n] + y[b,n,o]
// ---------------------------------------------------------------------------

// ---------------------------------------------------------------------------
// Stage 1: cp[b,o,n] = sum_c Wp[o,c] * cross[b,c,n] + bp[o]
// 64x64 tile per block, 4x4 per thread. LDS tiles k-major, pad 68.
// ---------------------------------------------------------------------------
__global__ __launch_bounds__(256) void k_proj(
    const float* __restrict__ Wp, const float* __restrict__ cross,
    const float* __restrict__ bp, float* __restrict__ cp)
{
    const int nb = blockIdx.x * 64;
    const int ob = blockIdx.y * 64;
    const int b  = blockIdx.z;
    __shared__ float As[16][68];  // [k][o-local]
    __shared__ float Bs[16][68];  // [k][n-local]
    const int t = threadIdx.x;
    const int tx = t & 15, ty = t >> 4;
    const float* crb = cross + b * BCN;
    float acc[4][4] = {};
    for (int k0 = 0; k0 < CC; k0 += 16) {
        {   // A tile: W_proj[ob..ob+64)[k0..k0+16), stored transposed
            const int r = t >> 2, kc = (t & 3) * 4;
            float4 v = *reinterpret_cast<const float4*>(Wp + (ob + r) * CC + k0 + kc);
            As[kc + 0][r] = v.x; As[kc + 1][r] = v.y;
            As[kc + 2][r] = v.z; As[kc + 3][r] = v.w;
        }
        {   // B tile: cross[b][k0..k0+16)[nb..nb+64), natural k-major
            const int r = t >> 4, nc = (t & 15) * 4;
            float4 v = *reinterpret_cast<const float4*>(crb + (k0 + r) * NN + nb + nc);
            Bs[r][nc + 0] = v.x; Bs[r][nc + 1] = v.y;
            Bs[r][nc + 2] = v.z; Bs[r][nc + 3] = v.w;
        }
        __syncthreads();
        #pragma unroll
        for (int kk = 0; kk < 16; ++kk) {
            float a0 = As[kk][ty * 4 + 0], a1 = As[kk][ty * 4 + 1];
            float a2 = As[kk][ty * 4 + 2], a3 = As[kk][ty * 4 + 3];
            float b0 = Bs[kk][tx * 4 + 0], b1 = Bs[kk][tx * 4 + 1];
            float b2 = Bs[kk][tx * 4 + 2], b3 = Bs[kk][tx * 4 + 3];
            acc[0][0] += a0 * b0; acc[0][1] += a0 * b1; acc[0][2] += a0 * b2; acc[0][3] += a0 * b3;
            acc[1][0] += a1 * b0; acc[1][1] += a1 * b1; acc[1][2] += a1 * b2; acc[1][3] += a1 * b3;
            acc[2][0] += a2 * b0; acc[2][1] += a2 * b1; acc[2][2] += a2 * b2; acc[2][3] += a2 * b3;
            acc[3][0] += a3 * b0; acc[3][1] += a3 * b1; acc[3][2] += a3 * b2; acc[3][3] += a3 * b3;
        }
        __syncthreads();
    }
    #pragma unroll
    for (int i = 0; i < 4; ++i) {
        const int o = ob + ty * 4 + i;
        const float bias = bp[o];
        float4 v;
        v.x = acc[i][0] + bias; v.y = acc[i][1] + bias;
        v.z = acc[i][2] + bias; v.w = acc[i][3] + bias;
        *reinterpret_cast<float4*>(cp + b * BCN + o * NN + nb + tx * 4) = v;
    }
}

// ---------------------------------------------------------------------------
// Stage 2: M[b,d,dd] = SCALE * sum_k cp_view[b,d,k] * cr_view[b,dd,k]
// Split-K over grid.x (12 chunks of 256), f32 atomics into zeroed M.
// ---------------------------------------------------------------------------
__global__ __launch_bounds__(256) void k_gram(
    const float* __restrict__ cp, const float* __restrict__ cross, float* __restrict__ Mm)
{
    const int b = blockIdx.y;
    const int kbase = blockIdx.x * 256;
    __shared__ float As[16][68];  // [k][d]
    __shared__ float Bs[16][68];  // [k][dd]
    const int t = threadIdx.x;
    const int tx = t & 15, ty = t >> 4;
    const float* cpb = cp + b * BCN;
    const float* crb = cross + b * BCN;
    float acc[4][4] = {};
    for (int k0 = kbase; k0 < kbase + 256; k0 += 16) {
        {
            const int r = t >> 2, kc = (t & 3) * 4;
            float4 v = *reinterpret_cast<const float4*>(cpb + r * K3 + k0 + kc);
            As[kc + 0][r] = v.x; As[kc + 1][r] = v.y; As[kc + 2][r] = v.z; As[kc + 3][r] = v.w;
            float4 w = *reinterpret_cast<const float4*>(crb + r * K3 + k0 + kc);
            Bs[kc + 0][r] = w.x; Bs[kc + 1][r] = w.y; Bs[kc + 2][r] = w.z; Bs[kc + 3][r] = w.w;
        }
        __syncthreads();
        #pragma unroll
        for (int kk = 0; kk < 16; ++kk) {
            float a0 = As[kk][ty * 4 + 0], a1 = As[kk][ty * 4 + 1];
            float a2 = As[kk][ty * 4 + 2], a3 = As[kk][ty * 4 + 3];
            float b0 = Bs[kk][tx * 4 + 0], b1 = Bs[kk][tx * 4 + 1];
            float b2 = Bs[kk][tx * 4 + 2], b3 = Bs[kk][tx * 4 + 3];
            acc[0][0] += a0 * b0; acc[0][1] += a0 * b1; acc[0][2] += a0 * b2; acc[0][3] += a0 * b3;
            acc[1][0] += a1 * b0; acc[1][1] += a1 * b1; acc[1][2] += a1 * b2; acc[1][3] += a1 * b3;
            acc[2][0] += a2 * b0; acc[2][1] += a2 * b1; acc[2][2] += a2 * b2; acc[2][3] += a2 * b3;
            acc[3][0] += a3 * b0; acc[3][1] += a3 * b1; acc[3][2] += a3 * b2; acc[3][3] += a3 * b3;
        }
        __syncthreads();
    }
    #pragma unroll
    for (int i = 0; i < 4; ++i)
        #pragma unroll
        for (int j = 0; j < 4; ++j)
            atomicAdd(Mm + b * 4096 + (ty * 4 + i) * 64 + (tx * 4 + j), acc[i][j] * SCALE);
}

// ---------------------------------------------------------------------------
// Stage 3: U[b,m,dd] = sum_d x_view[b,d,m] * M[b,d,dd]   (m in [0,3072))
// U ALIASES the cp buffer (cp dead after k_gram; stream-serialized).
// ---------------------------------------------------------------------------
__global__ __launch_bounds__(256) void k_xm(
    const float* __restrict__ x, const float* __restrict__ Mm, float* __restrict__ U)
{
    const int b = blockIdx.y;
    const int m0 = blockIdx.x * 64;
    __shared__ float Xs[64][68];  // [d][m-local]
    __shared__ float Ms[64][68];  // [d][dd]
    const int t = threadIdx.x;
    const int tx = t & 15, ty = t >> 4;
    const float* xb = x + b * BCN;
    const float* Mb = Mm + b * 4096;
    for (int i = t; i < 1024; i += 256) {
        const int r = i >> 4, c = (i & 15) * 4;
        float4 v = *reinterpret_cast<const float4*>(Mb + r * 64 + c);
        Ms[r][c + 0] = v.x; Ms[r][c + 1] = v.y; Ms[r][c + 2] = v.z; Ms[r][c + 3] = v.w;
        float4 w = *reinterpret_cast<const float4*>(xb + r * K3 + m0 + c);
        Xs[r][c + 0] = w.x; Xs[r][c + 1] = w.y; Xs[r][c + 2] = w.z; Xs[r][c + 3] = w.w;
    }
    __syncthreads();
    float acc[4][4] = {};
    #pragma unroll 8
    for (int d = 0; d < 64; ++d) {
        float a0 = Xs[d][ty * 4 + 0], a1 = Xs[d][ty * 4 + 1];
        float a2 = Xs[d][ty * 4 + 2], a3 = Xs[d][ty * 4 + 3];
        float b0 = Ms[d][tx * 4 + 0], b1 = Ms[d][tx * 4 + 1];
        float b2 = Ms[d][tx * 4 + 2], b3 = Ms[d][tx * 4 + 3];
        acc[0][0] += a0 * b0; acc[0][1] += a0 * b1; acc[0][2] += a0 * b2; acc[0][3] += a0 * b3;
        acc[1][0] += a1 * b0; acc[1][1] += a1 * b1; acc[1][2] += a1 * b2; acc[1][3] += a1 * b3;
        acc[2][0] += a2 * b0; acc[2][1] += a2 * b1; acc[2][2] += a2 * b2; acc[2][3] += a2 * b3;
        acc[3][0] += a3 * b0; acc[3][1] += a3 * b1; acc[3][2] += a3 * b2; acc[3][3] += a3 * b3;
    }
    #pragma unroll
    for (int i = 0; i < 4; ++i) {
        const int m = m0 + ty * 4 + i;
        float4 v;
        v.x = acc[i][0]; v.y = acc[i][1]; v.z = acc[i][2]; v.w = acc[i][3];
        *reinterpret_cast<float4*>(U + b * BCN + m * 64 + tx * 4) = v;
    }
}

// ---------------------------------------------------------------------------
// Stage 4: y[b,n,o] = sum_k U2[b,n,k] * Wd[o,k] + bd[o];
//          out[b,o,n] = x_ori[b,o,n] + y[b,n,o]     (fused residual)
// U2 = U flat viewed [256,768]. k_dep overwrites every element of d_out
// (whose first 128 KB hosted M as scratch — M fully consumed by k_xm).
// ---------------------------------------------------------------------------
__global__ __launch_bounds__(256) void k_dep(
    const float* __restrict__ U, const float* __restrict__ Wd, const float* __restrict__ bd,
    const float* __restrict__ x, float* __restrict__ out)
{
    const int n0 = blockIdx.x * 64;
    const int o0 = blockIdx.y * 64;
    const int b  = blockIdx.z;
    __shared__ float Us[16][68];  // [k][n-local]
    __shared__ float Ws[16][68];  // [k][o-local]
    const int t = threadIdx.x;
    const int tx = t & 15, ty = t >> 4;
    const float* Ub = U + b * BCN;
    float acc[4][4] = {};
    for (int k0 = 0; k0 < CC; k0 += 16) {
        {
            const int r = t >> 2, kc = (t & 3) * 4;
            float4 v = *reinterpret_cast<const float4*>(Ub + (n0 + r) * CC + k0 + kc);
            Us[kc + 0][r] = v.x; Us[kc + 1][r] = v.y; Us[kc + 2][r] = v.z; Us[kc + 3][r] = v.w;
            float4 w = *reinterpret_cast<const float4*>(Wd + (o0 + r) * CC + k0 + kc);
            Ws[kc + 0][r] = w.x; Ws[kc + 1][r] = w.y; Ws[kc + 2][r] = w.z; Ws[kc + 3][r] = w.w;
        }
        __syncthreads();
        #pragma unroll
        for (int kk = 0; kk < 16; ++kk) {
            float a0 = Ws[kk][ty * 4 + 0], a1 = Ws[kk][ty * 4 + 1];
            float a2 = Ws[kk][ty * 4 + 2], a3 = Ws[kk][ty * 4 + 3];
            float b0 = Us[kk][tx * 4 + 0], b1 = Us[kk][tx * 4 + 1];
            float b2 = Us[kk][tx * 4 + 2], b3 = Us[kk][tx * 4 + 3];
            acc[0][0] += a0 * b0; acc[0][1] += a0 * b1; acc[0][2] += a0 * b2; acc[0][3] += a0 * b3;
            acc[1][0] += a1 * b0; acc[1][1] += a1 * b1; acc[1][2] += a1 * b2; acc[1][3] += a1 * b3;
            acc[2][0] += a2 * b0; acc[2][1] += a2 * b1; acc[2][2] += a2 * b2; acc[2][3] += a2 * b3;
            acc[3][0] += a3 * b0; acc[3][1] += a3 * b1; acc[3][2] += a3 * b2; acc[3][3] += a3 * b3;
        }
        __syncthreads();
    }
    #pragma unroll
    for (int i = 0; i < 4; ++i) {
        const int o = o0 + ty * 4 + i;
        const float bias = bd[o];
        const int base = b * BCN + o * NN + n0 + tx * 4;
        float4 xr = *reinterpret_cast<const float4*>(x + base);
        float4 res;
        res.x = acc[i][0] + bias + xr.x;
        res.y = acc[i][1] + bias + xr.y;
        res.z = acc[i][2] + bias + xr.z;
        res.w = acc[i][3] + bias + xr.w;
        *reinterpret_cast<float4*>(out + base) = res;
    }
}

extern "C" void kernel_launch(void* const* d_in, const int* in_sizes, int n_in,
                              void* d_out, int out_size, void* d_ws, size_t ws_size,
                              hipStream_t stream) {
    const float* x_ori = (const float*)d_in[0];
    const float* cross = (const float*)d_in[1];
    const float* Wp    = (const float*)d_in[2];
    const float* bp    = (const float*)d_in[3];
    const float* Wd    = (const float*)d_in[4];
    const float* bd    = (const float*)d_in[5];
    float* out = (float*)d_out;

    // Scratch plan:
    //   d_ws  [0 .. 6,291,456): cp (f32 [8][768][256]); ALIASED by U
    //         (f32 [8][3072][64]) after k_gram — cp dead, stream-serialized.
    //   d_out [0 .. 131,072):   M (f32 [8][64][64]) scratch; fully consumed by
    //         k_xm, then k_dep overwrites every output element.
    float* cp = (float*)d_ws;
    float* U  = (float*)d_ws;
    float* Mm = (float*)d_out;

    hipMemsetAsync(Mm, 0, (size_t)BB * DD * DD * sizeof(float), stream);
    k_proj<<<dim3(NN / 64, CC / 64, BB), 256, 0, stream>>>(Wp, cross, bp, cp);
    k_gram<<<dim3(K3 / 256, BB), 256, 0, stream>>>(cp, cross, Mm);
    k_xm  <<<dim3(K3 / 64, BB), 256, 0, stream>>>(x_ori, Mm, U);
    k_dep <<<dim3(NN / 64, CC / 64, BB), 256, 0, stream>>>(U, Wd, bd, x_ori, out);
}

// Round 4
// 132.874 us; speedup vs baseline: 1.4762x; 1.4762x over previous
//
#include <hip/hip_runtime.h>

typedef unsigned short u16;
typedef short bf16x8 __attribute__((ext_vector_type(8)));
typedef float f32x4 __attribute__((ext_vector_type(4)));

#define BB 8
#define CC 768
#define NN 256
#define HH 12
#define DD 64
#define K3 3072          // H*N
#define BCN 196608       // C*N per batch
#define SCALE 0.125f
#define LDP 72           // LDS pitch in u16 (144 B rows: 16B-aligned, 2-way banks only)

__device__ __forceinline__ u16 f2b(float f) {
    union { float f; unsigned int i; } v; v.f = f;
    unsigned int r = v.i + 0x7FFFu + ((v.i >> 16) & 1u);
    return (u16)(r >> 16);
}

// ---------------------------------------------------------------------------
// Prep: build crT[b][n][c] (transpose of cross) and xT[b][m][d] (m=h*256+n,
// from x[b][d*12+h][n]) as bf16. Both are MFMA-operand copies living in d_out
// (dead before k_dep overwrites d_out). grid (4, 24, 8): y<12 -> xT (h=y),
// y>=12 -> crT (c0=(y-12)*64).
// ---------------------------------------------------------------------------
__global__ __launch_bounds__(256) void k_prep(
    const float* __restrict__ x, const float* __restrict__ cross, u16* __restrict__ outw)
{
    const int n0 = blockIdx.x * 64;
    const int b  = blockIdx.z;
    const int t  = threadIdx.x;
    __shared__ float T[64][68];
    u16* crT = outw;                        // [8][256][768]
    u16* xT  = outw + (size_t)BB * BCN;     // [8][3072][64]
    if (blockIdx.y < HH) {
        const int h = blockIdx.y;
        const float* xb = x + b * BCN;
        {   // load 64 d-rows (c = d*12+h) x 64 n
            const int d = t >> 2, fq = t & 3;
            const float* src = xb + (d * HH + h) * NN + n0;
            #pragma unroll
            for (int j = 0; j < 4; ++j) {
                const int nl = (fq + 4 * j) * 4;
                float4 v = *reinterpret_cast<const float4*>(src + nl);
                T[d][nl + 0] = v.x; T[d][nl + 1] = v.y; T[d][nl + 2] = v.z; T[d][nl + 3] = v.w;
            }
        }
        __syncthreads();
        {   // write xT[(h*256+n0+nn)*64 + d] transposed
            const int nn = t >> 2, dq = t & 3;
            u16* dst = xT + b * BCN + (h * NN + n0 + nn) * DD;
            #pragma unroll
            for (int j = 0; j < 4; ++j) {
                const int d0 = (dq + 4 * j) * 4;
                ushort4 w;
                w.x = f2b(T[d0 + 0][nn]); w.y = f2b(T[d0 + 1][nn]);
                w.z = f2b(T[d0 + 2][nn]); w.w = f2b(T[d0 + 3][nn]);
                *reinterpret_cast<ushort4*>(dst + d0) = w;
            }
        }
    } else {
        const int c0 = (blockIdx.y - HH) * 64;
        const float* crb = cross + b * BCN;
        {
            const int r = t >> 2, fq = t & 3;
            const float* src = crb + (c0 + r) * NN + n0;
            #pragma unroll
            for (int j = 0; j < 4; ++j) {
                const int nl = (fq + 4 * j) * 4;
                float4 v = *reinterpret_cast<const float4*>(src + nl);
                T[r][nl + 0] = v.x; T[r][nl + 1] = v.y; T[r][nl + 2] = v.z; T[r][nl + 3] = v.w;
            }
        }
        __syncthreads();
        {
            const int nn = t >> 2, cq = t & 3;
            u16* dst = crT + b * BCN + (n0 + nn) * CC + c0;
            #pragma unroll
            for (int j = 0; j < 4; ++j) {
                const int cl = (cq + 4 * j) * 4;
                ushort4 w;
                w.x = f2b(T[cl + 0][nn]); w.y = f2b(T[cl + 1][nn]);
                w.z = f2b(T[cl + 2][nn]); w.w = f2b(T[cl + 3][nn]);
                *reinterpret_cast<ushort4*>(dst + cl) = w;
            }
        }
    }
}

// ---------------------------------------------------------------------------
// Stage 1: cp[b,o,n] = sum_c Wp[o,c]*cross[b,c,n] + bp[o]   (bf16 out)
// NT-MFMA: A=Wp (f32->bf16 at staging), B=crT (bf16 copy). 64x64x64 tiles.
// ---------------------------------------------------------------------------
__global__ __launch_bounds__(256) void k_proj(
    const float* __restrict__ Wp, const u16* __restrict__ crT_all,
    const float* __restrict__ bp, u16* __restrict__ cp)
{
    const int n0 = blockIdx.x * 64;
    const int o0 = blockIdx.y * 64;
    const int b  = blockIdx.z;
    __shared__ __align__(16) u16 As[64 * LDP];
    __shared__ __align__(16) u16 Bs[64 * LDP];
    const int t = threadIdx.x;
    const int lane = t & 63, wave = t >> 6;
    const int q = lane >> 4, tx = lane & 15;
    const int wm = (wave & 1) * 32, wn = (wave >> 1) * 32;
    const u16* crT = crT_all + b * BCN;
    f32x4 acc[2][2] = {};
    for (int c0 = 0; c0 < CC; c0 += 64) {
        {   // A: Wp[o0+r][c0..+64) cvt
            const int r = t >> 2, cq = t & 3;
            const float* src = Wp + (o0 + r) * CC + c0;
            u16* dst = As + r * LDP;
            #pragma unroll
            for (int j = 0; j < 4; ++j) {
                const int cl = (cq + 4 * j) * 4;
                float4 v = *reinterpret_cast<const float4*>(src + cl);
                ushort4 w; w.x = f2b(v.x); w.y = f2b(v.y); w.z = f2b(v.z); w.w = f2b(v.w);
                *reinterpret_cast<ushort4*>(dst + cl) = w;
            }
        }
        {   // B: crT[n0+r][c0..+64) copy
            const int r = t >> 3, ch = (t & 7) * 8;
            *reinterpret_cast<uint4*>(Bs + r * LDP + ch) =
                *reinterpret_cast<const uint4*>(crT + (n0 + r) * CC + c0 + ch);
            *reinterpret_cast<uint4*>(Bs + (r + 32) * LDP + ch) =
                *reinterpret_cast<const uint4*>(crT + (n0 + r + 32) * CC + c0 + ch);
        }
        __syncthreads();
        #pragma unroll
        for (int kk = 0; kk < 2; ++kk) {
            bf16x8 a0 = *reinterpret_cast<bf16x8*>(As + (wm + tx) * LDP + kk * 32 + q * 8);
            bf16x8 a1 = *reinterpret_cast<bf16x8*>(As + (wm + 16 + tx) * LDP + kk * 32 + q * 8);
            bf16x8 b0 = *reinterpret_cast<bf16x8*>(Bs + (wn + tx) * LDP + kk * 32 + q * 8);
            bf16x8 b1 = *reinterpret_cast<bf16x8*>(Bs + (wn + 16 + tx) * LDP + kk * 32 + q * 8);
            acc[0][0] = __builtin_amdgcn_mfma_f32_16x16x32_bf16(a0, b0, acc[0][0], 0, 0, 0);
            acc[0][1] = __builtin_amdgcn_mfma_f32_16x16x32_bf16(a0, b1, acc[0][1], 0, 0, 0);
            acc[1][0] = __builtin_amdgcn_mfma_f32_16x16x32_bf16(a1, b0, acc[1][0], 0, 0, 0);
            acc[1][1] = __builtin_amdgcn_mfma_f32_16x16x32_bf16(a1, b1, acc[1][1], 0, 0, 0);
        }
        __syncthreads();
    }
    u16* cpb = cp + b * BCN;
    #pragma unroll
    for (int i = 0; i < 2; ++i)
        #pragma unroll
        for (int j = 0; j < 2; ++j)
            #pragma unroll
            for (int r = 0; r < 4; ++r) {
                const int o = o0 + wm + i * 16 + q * 4 + r;
                const int n = n0 + wn + j * 16 + tx;
                cpb[o * NN + n] = f2b(acc[i][j][r] + bp[o]);
            }
}

// ---------------------------------------------------------------------------
// Stage 2: G[b][dd][d] = SCALE * sum_k cross_view[dd][k]*cp_view[d][k]
// (G = M^T). Split-K 48 x 64; f32 atomics into zeroed G. A=cross (f32 cvt),
// B=cp (bf16 copy) — both k-contiguous flat views.
// ---------------------------------------------------------------------------
__global__ __launch_bounds__(256) void k_gram(
    const float* __restrict__ cross, const u16* __restrict__ cp, float* __restrict__ G)
{
    const int kb = blockIdx.x * 64;
    const int b  = blockIdx.y;
    __shared__ __align__(16) u16 As[64 * LDP];
    __shared__ __align__(16) u16 Bs[64 * LDP];
    const int t = threadIdx.x;
    const int lane = t & 63, wave = t >> 6;
    const int q = lane >> 4, tx = lane & 15;
    const int wm = (wave & 1) * 32, wn = (wave >> 1) * 32;
    const float* crb = cross + b * BCN;
    const u16* cpb = cp + b * BCN;
    f32x4 acc[2][2] = {};
    {
        const int r = t >> 2, cq = t & 3;
        const float* src = crb + r * K3 + kb;
        u16* dst = As + r * LDP;
        #pragma unroll
        for (int j = 0; j < 4; ++j) {
            const int cl = (cq + 4 * j) * 4;
            float4 v = *reinterpret_cast<const float4*>(src + cl);
            ushort4 w; w.x = f2b(v.x); w.y = f2b(v.y); w.z = f2b(v.z); w.w = f2b(v.w);
            *reinterpret_cast<ushort4*>(dst + cl) = w;
        }
    }
    {
        const int r = t >> 3, ch = (t & 7) * 8;
        *reinterpret_cast<uint4*>(Bs + r * LDP + ch) =
            *reinterpret_cast<const uint4*>(cpb + r * K3 + kb + ch);
        *reinterpret_cast<uint4*>(Bs + (r + 32) * LDP + ch) =
            *reinterpret_cast<const uint4*>(cpb + (r + 32) * K3 + kb + ch);
    }
    __syncthreads();
    #pragma unroll
    for (int kk = 0; kk < 2; ++kk) {
        bf16x8 a0 = *reinterpret_cast<bf16x8*>(As + (wm + tx) * LDP + kk * 32 + q * 8);
        bf16x8 a1 = *reinterpret_cast<bf16x8*>(As + (wm + 16 + tx) * LDP + kk * 32 + q * 8);
        bf16x8 b0 = *reinterpret_cast<bf16x8*>(Bs + (wn + tx) * LDP + kk * 32 + q * 8);
        bf16x8 b1 = *reinterpret_cast<bf16x8*>(Bs + (wn + 16 + tx) * LDP + kk * 32 + q * 8);
        acc[0][0] = __builtin_amdgcn_mfma_f32_16x16x32_bf16(a0, b0, acc[0][0], 0, 0, 0);
        acc[0][1] = __builtin_amdgcn_mfma_f32_16x16x32_bf16(a0, b1, acc[0][1], 0, 0, 0);
        acc[1][0] = __builtin_amdgcn_mfma_f32_16x16x32_bf16(a1, b0, acc[1][0], 0, 0, 0);
        acc[1][1] = __builtin_amdgcn_mfma_f32_16x16x32_bf16(a1, b1, acc[1][1], 0, 0, 0);
    }
    float* Gb = G + b * 4096;
    #pragma unroll
    for (int i = 0; i < 2; ++i)
        #pragma unroll
        for (int j = 0; j < 2; ++j)
            #pragma unroll
            for (int r = 0; r < 4; ++r) {
                const int dd = wm + i * 16 + q * 4 + r;
                const int d  = wn + j * 16 + tx;
                atomicAdd(Gb + dd * DD + d, acc[i][j][r] * SCALE);
            }
}

// ---------------------------------------------------------------------------
// Stage 3: U[b][m][dd] = sum_d xT[m][d]*G[dd][d].  A=xT (bf16), B=G (f32 cvt).
// Single K=64 chunk; U (bf16) aliases cp. 48 m-tiles x 8.
// ---------------------------------------------------------------------------
__global__ __launch_bounds__(256) void k_xm(
    const u16* __restrict__ xT_all, const float* __restrict__ G, u16* __restrict__ U)
{
    const int m0 = blockIdx.x * 64;
    const int b  = blockIdx.y;
    __shared__ __align__(16) u16 As[64 * LDP];
    __shared__ __align__(16) u16 Bs[64 * LDP];
    const int t = threadIdx.x;
    const int lane = t & 63, wave = t >> 6;
    const int q = lane >> 4, tx = lane & 15;
    const int wm = (wave & 1) * 32, wn = (wave >> 1) * 32;
    const u16* xT = xT_all + b * BCN;
    const float* Gb = G + b * 4096;
    f32x4 acc[2][2] = {};
    {
        const int r = t >> 3, ch = (t & 7) * 8;
        *reinterpret_cast<uint4*>(As + r * LDP + ch) =
            *reinterpret_cast<const uint4*>(xT + (m0 + r) * DD + ch);
        *reinterpret_cast<uint4*>(As + (r + 32) * LDP + ch) =
            *reinterpret_cast<const uint4*>(xT + (m0 + r + 32) * DD + ch);
    }
    {
        const int r = t >> 2, cq = t & 3;
        const float* src = Gb + r * DD;
        u16* dst = Bs + r * LDP;
        #pragma unroll
        for (int j = 0; j < 4; ++j) {
            const int cl = (cq + 4 * j) * 4;
            float4 v = *reinterpret_cast<const float4*>(src + cl);
            ushort4 w; w.x = f2b(v.x); w.y = f2b(v.y); w.z = f2b(v.z); w.w = f2b(v.w);
            *reinterpret_cast<ushort4*>(dst + cl) = w;
        }
    }
    __syncthreads();
    #pragma unroll
    for (int kk = 0; kk < 2; ++kk) {
        bf16x8 a0 = *reinterpret_cast<bf16x8*>(As + (wm + tx) * LDP + kk * 32 + q * 8);
        bf16x8 a1 = *reinterpret_cast<bf16x8*>(As + (wm + 16 + tx) * LDP + kk * 32 + q * 8);
        bf16x8 b0 = *reinterpret_cast<bf16x8*>(Bs + (wn + tx) * LDP + kk * 32 + q * 8);
        bf16x8 b1 = *reinterpret_cast<bf16x8*>(Bs + (wn + 16 + tx) * LDP + kk * 32 + q * 8);
        acc[0][0] = __builtin_amdgcn_mfma_f32_16x16x32_bf16(a0, b0, acc[0][0], 0, 0, 0);
        acc[0][1] = __builtin_amdgcn_mfma_f32_16x16x32_bf16(a0, b1, acc[0][1], 0, 0, 0);
        acc[1][0] = __builtin_amdgcn_mfma_f32_16x16x32_bf16(a1, b0, acc[1][0], 0, 0, 0);
        acc[1][1] = __builtin_amdgcn_mfma_f32_16x16x32_bf16(a1, b1, acc[1][1], 0, 0, 0);
    }
    u16* Ub = U + b * BCN;
    #pragma unroll
    for (int i = 0; i < 2; ++i)
        #pragma unroll
        for (int j = 0; j < 2; ++j)
            #pragma unroll
            for (int r = 0; r < 4; ++r) {
                const int m  = m0 + wm + i * 16 + q * 4 + r;
                const int dd = wn + j * 16 + tx;
                Ub[m * DD + dd] = f2b(acc[i][j][r]);
            }
}

// ---------------------------------------------------------------------------
// Stage 4: out[b,o,n] = x[b,o,n] + bd[o] + sum_k Wd[o,k]*U2[n,k]
// A=Wd (f32 cvt), B=U2 = U flat viewed [256][768] (bf16, k-contig).
// ---------------------------------------------------------------------------
__global__ __launch_bounds__(256) void k_dep(
    const float* __restrict__ Wd, const u16* __restrict__ U,
    const float* __restrict__ bd, const float* __restrict__ x, float* __restrict__ out)
{
    const int n0 = blockIdx.x * 64;
    const int o0 = blockIdx.y * 64;
    const int b  = blockIdx.z;
    __shared__ __align__(16) u16 As[64 * LDP];
    __shared__ __align__(16) u16 Bs[64 * LDP];
    const int t = threadIdx.x;
    const int lane = t & 63, wave = t >> 6;
    const int q = lane >> 4, tx = lane & 15;
    const int wm = (wave & 1) * 32, wn = (wave >> 1) * 32;
    const u16* Ub = U + b * BCN;
    f32x4 acc[2][2] = {};
    for (int c0 = 0; c0 < CC; c0 += 64) {
        {
            const int r = t >> 2, cq = t & 3;
            const float* src = Wd + (o0 + r) * CC + c0;
            u16* dst = As + r * LDP;
            #pragma unroll
            for (int j = 0; j < 4; ++j) {
                const int cl = (cq + 4 * j) * 4;
                float4 v = *reinterpret_cast<const float4*>(src + cl);
                ushort4 w; w.x = f2b(v.x); w.y = f2b(v.y); w.z = f2b(v.z); w.w = f2b(v.w);
                *reinterpret_cast<ushort4*>(dst + cl) = w;
            }
        }
        {
            const int r = t >> 3, ch = (t & 7) * 8;
            *reinterpret_cast<uint4*>(Bs + r * LDP + ch) =
                *reinterpret_cast<const uint4*>(Ub + (n0 + r) * CC + c0 + ch);
            *reinterpret_cast<uint4*>(Bs + (r + 32) * LDP + ch) =
                *reinterpret_cast<const uint4*>(Ub + (n0 + r + 32) * CC + c0 + ch);
        }
        __syncthreads();
        #pragma unroll
        for (int kk = 0; kk < 2; ++kk) {
            bf16x8 a0 = *reinterpret_cast<bf16x8*>(As + (wm + tx) * LDP + kk * 32 + q * 8);
            bf16x8 a1 = *reinterpret_cast<bf16x8*>(As + (wm + 16 + tx) * LDP + kk * 32 + q * 8);
            bf16x8 b0 = *reinterpret_cast<bf16x8*>(Bs + (wn + tx) * LDP + kk * 32 + q * 8);
            bf16x8 b1 = *reinterpret_cast<bf16x8*>(Bs + (wn + 16 + tx) * LDP + kk * 32 + q * 8);
            acc[0][0] = __builtin_amdgcn_mfma_f32_16x16x32_bf16(a0, b0, acc[0][0], 0, 0, 0);
            acc[0][1] = __builtin_amdgcn_mfma_f32_16x16x32_bf16(a0, b1, acc[0][1], 0, 0, 0);
            acc[1][0] = __builtin_amdgcn_mfma_f32_16x16x32_bf16(a1, b0, acc[1][0], 0, 0, 0);
            acc[1][1] = __builtin_amdgcn_mfma_f32_16x16x32_bf16(a1, b1, acc[1][1], 0, 0, 0);
        }
        __syncthreads();
    }
    #pragma unroll
    for (int i = 0; i < 2; ++i)
        #pragma unroll
        for (int j = 0; j < 2; ++j)
            #pragma unroll
            for (int r = 0; r < 4; ++r) {
                const int o = o0 + wm + i * 16 + q * 4 + r;
                const int n = n0 + wn + j * 16 + tx;
                const int idx = b * BCN + o * NN + n;
                out[idx] = acc[i][j][r] + bd[o] + x[idx];
            }
}

extern "C" void kernel_launch(void* const* d_in, const int* in_sizes, int n_in,
                              void* d_out, int out_size, void* d_ws, size_t ws_size,
                              hipStream_t stream) {
    const float* x_ori = (const float*)d_in[0];
    const float* cross = (const float*)d_in[1];
    const float* Wp    = (const float*)d_in[2];
    const float* bp    = (const float*)d_in[3];
    const float* Wd    = (const float*)d_in[4];
    const float* bd    = (const float*)d_in[5];
    float* out = (float*)d_out;

    // ws: [0, 3,145,728): cp bf16 [8][768][256]; ALIASED by U bf16 [8][3072][64]
    //     after k_gram (cp dead). [3,145,728, +131,072): G f32 [8][64][64].
    // d_out: crT bf16 (3.1 MB) + xT bf16 (3.1 MB) scratch from k_prep; both
    //     dead before k_dep fully overwrites d_out.
    u16*   cp = (u16*)d_ws;
    u16*   U  = (u16*)d_ws;
    float* G  = (float*)((char*)d_ws + (size_t)BB * BCN * sizeof(u16));
    u16*   prep = (u16*)d_out;                       // crT then xT
    const u16* crT = prep;
    const u16* xT  = prep + (size_t)BB * BCN;

    hipMemsetAsync(G, 0, (size_t)BB * DD * DD * sizeof(float), stream);
    k_prep<<<dim3(4, 24, BB), 256, 0, stream>>>(x_ori, cross, prep);
    k_proj<<<dim3(4, 12, BB), 256, 0, stream>>>(Wp, crT, bp, cp);
    k_gram<<<dim3(48, BB), 256, 0, stream>>>(cross, cp, G);
    k_xm  <<<dim3(48, BB), 256, 0, stream>>>(xT, G, U);
    k_dep <<<dim3(4, 12, BB), 256, 0, stream>>>(Wd, U, bd, x_ori, out);
}